// Round 9
// baseline (388.492 us; speedup 1.0000x reference)
//
#include <hip/hip_runtime.h>

// FGKAN scoring kernel for MI355X (gfx950).
//
// Restructure: x@W1 = h_set@W1_top + path@W1_bot.
//   - h_set is a SUM of entity rows  -> precompute P_ent = ent @ W1_top
//   - path is a PRODUCT of relation rows, 32 relations -> precompute
//     P_rel1[32][64] and P_rel2[1024][64] @ W1_bot.
//
// R8 post-mortem: k_main 91.5us (DPP/deferred-norm/merged bought ~3% -> it is
// memory-side bound: random gathers at ~3.5TB/s L3 traffic). But total=226.8
// means ~135us sits in proj kernels + per-replay overhead, split unknown.
// R9: disambiguate. (1) fuse proj_ent+proj_rel into ONE launch, rel part now
// LDS-tiled GEMM too; (2) revert merged->split tables (merged = no gain).
// k_main byte-identical as control. Total ~190 => ~80us fixed overhead is real
// (next: cooperative mega-kernel). Total ~115 => proj was the cost (done).
//
// d_ws layout: Prel1 (8KB) | Prel2 (256KB) | Pent (25.6MB)

#define NE   100000
#define NR   32
#define DIMD 64
#define BB   4096
#define TT   32
#define BT   (BB * TT)

#define ENT_BLOCKS 1563   // ceil(NE/64)
#define REL_BLOCKS 17     // ceil(1056/64)

__device__ __forceinline__ float sigf(float x) { return 1.0f / (1.0f + __expf(-x)); }
__device__ __forceinline__ float4 ld4(const float* p) {
    return *reinterpret_cast<const float4*>(p);
}
__device__ __forceinline__ void st4(float* p, float4 v) {
    *reinterpret_cast<float4*>(p) = v;
}

// v_add_f32 with DPP row_ror:N source (16-lane row rotate) — VALU-speed reduce.
template <int CTRL>
__device__ __forceinline__ float dpp_add(float x) {
    int r = __builtin_amdgcn_update_dpp(0, __builtin_bit_cast(int, x), CTRL,
                                        0xf, 0xf, true);
    return x + __builtin_bit_cast(float, r);
}
// sum across each 16-lane row (all lanes get the row total)
__device__ __forceinline__ float reduce16(float x) {
    x = dpp_add<0x121>(x);  // row_ror:1
    x = dpp_add<0x122>(x);  // row_ror:2
    x = dpp_add<0x124>(x);  // row_ror:4
    x = dpp_add<0x128>(x);  // row_ror:8
    return x;
}

// ---------------------------------------------------------------- precompute
// One fused launch, grid = ENT_BLOCKS + REL_BLOCKS.
// blocks [0, ENT_BLOCKS): Pent[e] = ent[e] @ W1_top, 64 rows/block.
// blocks [ENT_BLOCKS, +REL_BLOCKS): rows ro in [0,1088):
//   ro < 1024  : Prel2[ro] = (rel[ro>>5] * rel[ro&31]) @ W1_bot
//   1024..1055 : Prel1[ro-1024] = rel[ro-1024] @ W1_bot
// Same LDS-tiled GEMM for both: input rows + W half staged in LDS,
// 4 rows x float4 register blocking per thread.
__global__ __launch_bounds__(256) void k_proj(const float* __restrict__ ent,
                                              const float* __restrict__ rel,
                                              const float* __restrict__ W1,
                                              float* __restrict__ Pent,
                                              float* __restrict__ Prel1,
                                              float* __restrict__ Prel2) {
    __shared__ float sW[64][68];  // W1 half: sW[k][d]
    __shared__ float sR[64][68];  // input rows: sR[r][k]
    const int tid = threadIdx.x;
    const bool isEnt = blockIdx.x < ENT_BLOCKS;
    const int base = isEnt ? blockIdx.x * 64 : (blockIdx.x - ENT_BLOCKS) * 64;

    // stage W half + 64 input rows; 4 float4 per thread each
#pragma unroll
    for (int i = 0; i < 4; ++i) {
        const int idx = tid + 256 * i;        // 0..1023
        const int r = idx >> 4;               // 0..63
        const int c = idx & 15;               // float4 chunk
        const int wrow = isEnt ? r : (DIMD + r);
        const float4 wv = ld4(W1 + wrow * DIMD + 4 * c);
        sW[r][4 * c + 0] = wv.x; sW[r][4 * c + 1] = wv.y;
        sW[r][4 * c + 2] = wv.z; sW[r][4 * c + 3] = wv.w;
        float4 rv;
        if (isEnt) {
            const int er = (base + r < NE) ? (base + r) : (NE - 1);
            rv = ld4(ent + er * DIMD + 4 * c);
        } else {
            const int ro = base + r;
            if (ro < 1024) {
                const float4 a = ld4(rel + (ro >> 5) * DIMD + 4 * c);
                const float4 b = ld4(rel + (ro & 31) * DIMD + 4 * c);
                rv = make_float4(a.x * b.x, a.y * b.y, a.z * b.z, a.w * b.w);
            } else {
                const int rr = (ro < 1056) ? (ro - 1024) : 0;
                rv = ld4(rel + rr * DIMD + 4 * c);
            }
        }
        sR[r][4 * c + 0] = rv.x; sR[r][4 * c + 1] = rv.y;
        sR[r][4 * c + 2] = rv.z; sR[r][4 * c + 3] = rv.w;
    }
    __syncthreads();

    const int q = tid & 15;       // output float4 chunk
    const int trow = tid >> 4;    // 0..15 -> rows 4*trow .. 4*trow+3
    float4 acc0 = make_float4(0.f, 0.f, 0.f, 0.f);
    float4 acc1 = acc0, acc2 = acc0, acc3 = acc0;

#pragma unroll
    for (int kk = 0; kk < 16; ++kk) {
        const float4 r0 = ld4(&sR[4 * trow + 0][4 * kk]);
        const float4 r1 = ld4(&sR[4 * trow + 1][4 * kk]);
        const float4 r2 = ld4(&sR[4 * trow + 2][4 * kk]);
        const float4 r3 = ld4(&sR[4 * trow + 3][4 * kk]);
#pragma unroll
        for (int i = 0; i < 4; ++i) {
            const float4 wv = ld4(&sW[4 * kk + i][4 * q]);
            const float s0 = (i == 0) ? r0.x : (i == 1) ? r0.y : (i == 2) ? r0.z : r0.w;
            const float s1 = (i == 0) ? r1.x : (i == 1) ? r1.y : (i == 2) ? r1.z : r1.w;
            const float s2 = (i == 0) ? r2.x : (i == 1) ? r2.y : (i == 2) ? r2.z : r2.w;
            const float s3 = (i == 0) ? r3.x : (i == 1) ? r3.y : (i == 2) ? r3.z : r3.w;
            acc0.x = fmaf(s0, wv.x, acc0.x); acc0.y = fmaf(s0, wv.y, acc0.y);
            acc0.z = fmaf(s0, wv.z, acc0.z); acc0.w = fmaf(s0, wv.w, acc0.w);
            acc1.x = fmaf(s1, wv.x, acc1.x); acc1.y = fmaf(s1, wv.y, acc1.y);
            acc1.z = fmaf(s1, wv.z, acc1.z); acc1.w = fmaf(s1, wv.w, acc1.w);
            acc2.x = fmaf(s2, wv.x, acc2.x); acc2.y = fmaf(s2, wv.y, acc2.y);
            acc2.z = fmaf(s2, wv.z, acc2.z); acc2.w = fmaf(s2, wv.w, acc2.w);
            acc3.x = fmaf(s3, wv.x, acc3.x); acc3.y = fmaf(s3, wv.y, acc3.y);
            acc3.z = fmaf(s3, wv.z, acc3.z); acc3.w = fmaf(s3, wv.w, acc3.w);
        }
    }

#pragma unroll
    for (int i = 0; i < 4; ++i) {
        const float4 a = (i == 0) ? acc0 : (i == 1) ? acc1 : (i == 2) ? acc2 : acc3;
        const int ro = base + 4 * trow + i;
        if (isEnt) {
            if (ro < NE) st4(Pent + (size_t)ro * DIMD + 4 * q, a);
        } else {
            if (ro < 1024) st4(Prel2 + ro * DIMD + 4 * q, a);
            else if (ro < 1056) st4(Prel1 + (ro - 1024) * DIMD + 4 * q, a);
        }
    }
}

// ---------------------------------------------------------------- main
// One block per b. Wave w = branch (0:uis->e_u, 1:ipt->e_i, 2:upt->e_p_u,
// 3:iot->e_p_i). Lane = (g = t-subgroup in [0,4), q = float4 chunk in [0,16)).
// entT/eshift, pentT/pshift: table bases+log2 row strides.
__global__ __launch_bounds__(256) void k_main(
    const int* __restrict__ items,
    const int* __restrict__ uh, const int* __restrict__ ur, const int* __restrict__ ut,
    const int* __restrict__ ih, const int* __restrict__ ir, const int* __restrict__ itp,
    const int* __restrict__ ph, const int* __restrict__ pr, const int* __restrict__ pt,
    const int* __restrict__ oh, const int* __restrict__ orr, const int* __restrict__ ot,
    const float* __restrict__ entT, int eshift,
    const float* __restrict__ pentT, int pshift,
    const float* __restrict__ W2,
    const float* __restrict__ Prel1, const float* __restrict__ Prel2,
    float* __restrict__ out) {
    const int b = blockIdx.x;
    const int tid = threadIdx.x;
    const int w = tid >> 6;
    const int lane = tid & 63;
    const int g = lane >> 4;
    const int q = lane & 15;

    const int* hp;
    const int* rp;
    const int* tp;
    switch (w) {
        case 0: hp = uh; rp = ur; tp = ut; break;
        case 1: hp = ih; rp = ir; tp = itp; break;
        case 2: hp = ph; rp = pr; tp = pt; break;
        default: hp = oh; rp = orr; tp = ot; break;
    }

    // stage this block's indices in LDS (wave-private; same wave writes/reads)
    __shared__ int sidx[4][3][2][TT];
    {
        const int l = lane >> 5;
        const int t0 = lane & 31;
        const int off = l * BT + b * TT + t0;
        sidx[w][0][l][t0] = hp[off];
        sidx[w][1][l][t0] = rp[off];
        sidx[w][2][l][t0] = tp[off];
    }
    const int item_idx = (w == 1) ? items[b] : 0;

    const float4 w2v = ld4(W2 + 4 * q);

    // ---- Phase A: per-lane partial dots d0/d1 for all 8 t's (no reduces yet)
    float d0[8], d1[8];
    float4 accH = make_float4(0.f, 0.f, 0.f, 0.f);
#pragma unroll
    for (int p = 0; p < 8; ++p) {
        const int t = 4 * p + g;
        const int ih0 = sidx[w][0][0][t];
        const int ih1 = sidx[w][0][1][t];
        const int ir0 = sidx[w][1][0][t];
        const int ir1 = sidx[w][1][1][t];
        const float4 A0 = ld4(pentT + ((size_t)ih0 << pshift) + 4 * q);
        const float4 H  = ld4(entT + ((size_t)ih0 << eshift) + 4 * q);
        const float4 A1 = ld4(pentT + ((size_t)ih1 << pshift) + 4 * q);
        const float4 R0 = ld4(Prel1 + (ir0 << 6) + 4 * q);
        const float4 R2 = ld4(Prel2 + ((ir0 * 32 + ir1) << 6) + 4 * q);

        accH.x += H.x; accH.y += H.y; accH.z += H.z; accH.w += H.w;

        float v = sigf(A0.x + R0.x) * w2v.x;
        v = fmaf(sigf(A0.y + R0.y), w2v.y, v);
        v = fmaf(sigf(A0.z + R0.z), w2v.z, v);
        v = fmaf(sigf(A0.w + R0.w), w2v.w, v);
        d0[p] = v;

        float u = sigf(A0.x + A1.x + R2.x) * w2v.x;
        u = fmaf(sigf(A0.y + A1.y + R2.y), w2v.y, u);
        u = fmaf(sigf(A0.z + A1.z + R2.z), w2v.z, u);
        u = fmaf(sigf(A0.w + A1.w + R2.w), w2v.w, u);
        d1[p] = u;
    }

    // ---- Phase B: batched 16-lane DPP reduces; e = exp(sigmoid(dot)).
    // (logits in (0,1) -> no max-subtraction needed; normalization deferred)
    float e0[8], e1[8];
    float s0 = 0.0f, s1 = 0.0f;
#pragma unroll
    for (int p = 0; p < 8; ++p) {
        e0[p] = __expf(sigf(reduce16(d0[p])));
        e1[p] = __expf(sigf(reduce16(d1[p])));
        s0 += e0[p];
        s1 += e1[p];
    }
    s0 += __shfl_xor(s0, 16, 64);
    s0 += __shfl_xor(s0, 32, 64);
    s1 += __shfl_xor(s1, 16, 64);
    s1 += __shfl_xor(s1, 32, 64);

    // ---- Phase C: unnormalized weighted t-emb sums
    float4 acc0 = make_float4(0.f, 0.f, 0.f, 0.f);
    float4 acc1 = acc0;
#pragma unroll
    for (int p = 0; p < 8; ++p) {
        const int t = 4 * p + g;
        const int it0 = sidx[w][2][0][t];
        const int it1 = sidx[w][2][1][t];
        const float4 T0 = ld4(entT + ((size_t)it0 << eshift) + 4 * q);
        const float4 T1 = ld4(entT + ((size_t)it1 << eshift) + 4 * q);
        acc0.x = fmaf(e0[p], T0.x, acc0.x); acc0.y = fmaf(e0[p], T0.y, acc0.y);
        acc0.z = fmaf(e0[p], T0.z, acc0.z); acc0.w = fmaf(e0[p], T0.w, acc0.w);
        acc1.x = fmaf(e1[p], T1.x, acc1.x); acc1.y = fmaf(e1[p], T1.y, acc1.y);
        acc1.z = fmaf(e1[p], T1.z, acc1.z); acc1.w = fmaf(e1[p], T1.w, acc1.w);
    }

    const float inv0 = 1.0f / s0;
    const float inv1 = 1.0f / s1;
    float4 v;
    v.x = fmaf(acc0.x, inv0, fmaf(acc1.x, inv1, 0.03125f * accH.x));
    v.y = fmaf(acc0.y, inv0, fmaf(acc1.y, inv1, 0.03125f * accH.y));
    v.z = fmaf(acc0.z, inv0, fmaf(acc1.z, inv1, 0.03125f * accH.z));
    v.w = fmaf(acc0.w, inv0, fmaf(acc1.w, inv1, 0.03125f * accH.w));

    // reduce across the 4 t-subgroups
    v.x += __shfl_xor(v.x, 16, 64); v.x += __shfl_xor(v.x, 32, 64);
    v.y += __shfl_xor(v.y, 16, 64); v.y += __shfl_xor(v.y, 32, 64);
    v.z += __shfl_xor(v.z, 16, 64); v.z += __shfl_xor(v.z, 32, 64);
    v.w += __shfl_xor(v.w, 16, 64); v.w += __shfl_xor(v.w, 32, 64);

    if (w == 1) {  // item branch additionally adds ent[items[b]]
        const float4 iv = ld4(entT + ((size_t)item_idx << eshift) + 4 * q);
        v.x += iv.x; v.y += iv.y; v.z += iv.z; v.w += iv.w;
    }

    __shared__ float vec[4][DIMD];
    if (g == 0) {
        vec[w][4 * q + 0] = v.x;
        vec[w][4 * q + 1] = v.y;
        vec[w][4 * q + 2] = v.z;
        vec[w][4 * q + 3] = v.w;
    }
    __syncthreads();

    // score = sigmoid( sum_d e_u*e_p_i + e_p_u*e_i )
    if (tid < 64) {
        float z = fmaf(vec[0][tid], vec[3][tid], vec[2][tid] * vec[1][tid]);
#pragma unroll
        for (int m = 1; m < 64; m <<= 1) z += __shfl_xor(z, m, 64);
        if (tid == 0) out[b] = sigf(z);
    }
    if (b == 0 && tid == 0) out[BB] = 0.0f;  // kge_loss
}

extern "C" void kernel_launch(void* const* d_in, const int* in_sizes, int n_in,
                              void* d_out, int out_size, void* d_ws, size_t ws_size,
                              hipStream_t stream) {
    const int* items = (const int*)d_in[0];
    const int* uh = (const int*)d_in[1];
    const int* ur = (const int*)d_in[2];
    const int* ut = (const int*)d_in[3];
    const int* ih = (const int*)d_in[4];
    const int* ir = (const int*)d_in[5];
    const int* itp = (const int*)d_in[6];
    const int* ph = (const int*)d_in[7];
    const int* pr = (const int*)d_in[8];
    const int* pt = (const int*)d_in[9];
    const int* oh = (const int*)d_in[10];
    const int* orr = (const int*)d_in[11];
    const int* ot = (const int*)d_in[12];
    const float* ent = (const float*)d_in[13];
    const float* rel = (const float*)d_in[14];
    const float* W1 = (const float*)d_in[15];
    const float* W2 = (const float*)d_in[16];
    float* out = (float*)d_out;

    float* Prel1 = (float*)d_ws;                    // 32*64   = 2048 f
    float* Prel2 = Prel1 + NR * DIMD;               // 1024*64 = 65536 f
    float* Pent = Prel2 + 1024 * DIMD;              // 100000*64 = 25.6MB

    hipLaunchKernelGGL(k_proj, dim3(ENT_BLOCKS + REL_BLOCKS), dim3(256), 0,
                       stream, ent, rel, W1, Pent, Prel1, Prel2);
    hipLaunchKernelGGL(k_main, dim3(BB), dim3(256), 0, stream, items, uh, ur, ut,
                       ih, ir, itp, ph, pr, pt, oh, orr, ot, ent, 6, Pent, 6,
                       W2, Prel1, Prel2, out);
}

// Round 10
// 197.198 us; speedup vs baseline: 1.9701x; 1.9701x over previous
//
#include <hip/hip_runtime.h>

// FGKAN scoring kernel for MI355X (gfx950).
//
// Restructure: x@W1 = h_set@W1_top + path@W1_bot.
//   - h_set is a SUM of entity rows  -> precompute P_ent = ent @ W1_top
//   - path is a PRODUCT of relation rows, 32 relations -> precompute
//     P_rel1[32][64] and P_rel2[1024][64] @ W1_bot.
//
// R9 post-mortem: fused k_proj spilled (VGPR 256, occ 10%, 245MB scratch
// writes) -> 211us. Reverted to R4's separate non-spilling proj kernels.
// Accounting across R3/R8/R9 pins a fixed ~85us harness replay residual;
// controllables are proj (~55us) + k_main (91.5us, 311MB L2-miss @ 3.4TB/s,
// ~54% hit over 51MB f32 tables).
// R10: bf16 merged [entB|PentB] 256B rows (25.6MB table): halves gather
// bytes, H+A0 become adjacent lines, table fits cache-scale. Prel stays f32.
//
// d_ws layout: Prel1 (8KB f32) | Prel2 (256KB f32) | tab (NE x 128 bf16 = 25.6MB)

#define NE   100000
#define NR   32
#define DIMD 64
#define BB   4096
#define TT   32
#define BT   (BB * TT)

__device__ __forceinline__ float sigf(float x) { return 1.0f / (1.0f + __expf(-x)); }
__device__ __forceinline__ float4 ld4(const float* p) {
    return *reinterpret_cast<const float4*>(p);
}

// bf16 helpers (manual RNE pack / shift unpack)
__device__ __forceinline__ float b2f(unsigned short u) {
    return __builtin_bit_cast(float, ((unsigned)u) << 16);
}
__device__ __forceinline__ unsigned short f2b(float x) {
    unsigned b = __builtin_bit_cast(unsigned, x);
    b += 0x7FFF + ((b >> 16) & 1);
    return (unsigned short)(b >> 16);
}
__device__ __forceinline__ float4 ldb4(const unsigned short* p) {
    ushort4 v = *reinterpret_cast<const ushort4*>(p);
    return make_float4(b2f(v.x), b2f(v.y), b2f(v.z), b2f(v.w));
}

// v_add_f32 with DPP row_ror:N source (16-lane row rotate) — VALU-speed reduce.
template <int CTRL>
__device__ __forceinline__ float dpp_add(float x) {
    int r = __builtin_amdgcn_update_dpp(0, __builtin_bit_cast(int, x), CTRL,
                                        0xf, 0xf, true);
    return x + __builtin_bit_cast(float, r);
}
__device__ __forceinline__ float reduce16(float x) {
    x = dpp_add<0x121>(x);  // row_ror:1
    x = dpp_add<0x122>(x);  // row_ror:2
    x = dpp_add<0x124>(x);  // row_ror:4
    x = dpp_add<0x128>(x);  // row_ror:8
    return x;
}

// ---------------------------------------------------------------- precompute
// R4-structure LDS-tiled GEMM (known non-spilling), bf16 merged epilogue:
// tab row r (256B) = [ entB: 64 bf16 | PentB: 64 bf16 ].
__global__ __launch_bounds__(256) void k_proj_ent(const float* __restrict__ ent,
                                                  const float* __restrict__ W1,
                                                  unsigned short* __restrict__ tab) {
    __shared__ float sW[64][68];
    __shared__ float sR[64][68];
    const int tid = threadIdx.x;
    const int row0 = blockIdx.x * 64;

#pragma unroll
    for (int i = 0; i < 4; ++i) {
        const int idx = tid + 256 * i;        // 0..1023
        const int r = idx >> 4;
        const int c = idx & 15;
        const float4 wv = ld4(W1 + r * DIMD + 4 * c);
        sW[r][4 * c + 0] = wv.x; sW[r][4 * c + 1] = wv.y;
        sW[r][4 * c + 2] = wv.z; sW[r][4 * c + 3] = wv.w;
        const int er = (row0 + r < NE) ? (row0 + r) : (NE - 1);
        const float4 rv = ld4(ent + er * DIMD + 4 * c);
        sR[r][4 * c + 0] = rv.x; sR[r][4 * c + 1] = rv.y;
        sR[r][4 * c + 2] = rv.z; sR[r][4 * c + 3] = rv.w;
    }
    __syncthreads();

    const int q = tid & 15;
    const int trow = tid >> 4;
    float4 acc0 = make_float4(0.f, 0.f, 0.f, 0.f);
    float4 acc1 = acc0, acc2 = acc0, acc3 = acc0;

#pragma unroll
    for (int kk = 0; kk < 16; ++kk) {
        const float4 r0 = ld4(&sR[4 * trow + 0][4 * kk]);
        const float4 r1 = ld4(&sR[4 * trow + 1][4 * kk]);
        const float4 r2 = ld4(&sR[4 * trow + 2][4 * kk]);
        const float4 r3 = ld4(&sR[4 * trow + 3][4 * kk]);
#pragma unroll
        for (int i = 0; i < 4; ++i) {
            const float4 wv = ld4(&sW[4 * kk + i][4 * q]);
            const float s0 = (i == 0) ? r0.x : (i == 1) ? r0.y : (i == 2) ? r0.z : r0.w;
            const float s1 = (i == 0) ? r1.x : (i == 1) ? r1.y : (i == 2) ? r1.z : r1.w;
            const float s2 = (i == 0) ? r2.x : (i == 1) ? r2.y : (i == 2) ? r2.z : r2.w;
            const float s3 = (i == 0) ? r3.x : (i == 1) ? r3.y : (i == 2) ? r3.z : r3.w;
            acc0.x = fmaf(s0, wv.x, acc0.x); acc0.y = fmaf(s0, wv.y, acc0.y);
            acc0.z = fmaf(s0, wv.z, acc0.z); acc0.w = fmaf(s0, wv.w, acc0.w);
            acc1.x = fmaf(s1, wv.x, acc1.x); acc1.y = fmaf(s1, wv.y, acc1.y);
            acc1.z = fmaf(s1, wv.z, acc1.z); acc1.w = fmaf(s1, wv.w, acc1.w);
            acc2.x = fmaf(s2, wv.x, acc2.x); acc2.y = fmaf(s2, wv.y, acc2.y);
            acc2.z = fmaf(s2, wv.z, acc2.z); acc2.w = fmaf(s2, wv.w, acc2.w);
            acc3.x = fmaf(s3, wv.x, acc3.x); acc3.y = fmaf(s3, wv.y, acc3.y);
            acc3.z = fmaf(s3, wv.z, acc3.z); acc3.w = fmaf(s3, wv.w, acc3.w);
        }
    }

    const int orow = row0 + 4 * trow;
#pragma unroll
    for (int i = 0; i < 4; ++i) {
        if (orow + i < NE) {
            const float4 a = (i == 0) ? acc0 : (i == 1) ? acc1 : (i == 2) ? acc2 : acc3;
            unsigned short* rowp = tab + ((size_t)(orow + i) << 7);
            ushort4 ev, pv;
            ev.x = f2b(sR[4 * trow + i][4 * q + 0]);
            ev.y = f2b(sR[4 * trow + i][4 * q + 1]);
            ev.z = f2b(sR[4 * trow + i][4 * q + 2]);
            ev.w = f2b(sR[4 * trow + i][4 * q + 3]);
            pv.x = f2b(a.x); pv.y = f2b(a.y); pv.z = f2b(a.z); pv.w = f2b(a.w);
            *reinterpret_cast<ushort4*>(rowp + 4 * q) = ev;
            *reinterpret_cast<ushort4*>(rowp + 64 + 4 * q) = pv;
        }
    }
}

// rows [0,1024)    : P_rel2[r0*32+r1][d] = sum_k rel[r0][k]*rel[r1][k]*W1[64+k][d]
// rows [1024,1056) : P_rel1[r][d]        = sum_k rel[r][k]*W1[64+k][d]
__global__ __launch_bounds__(256) void k_proj_rel(const float* __restrict__ rel,
                                                  const float* __restrict__ W1,
                                                  float* __restrict__ Prel1,
                                                  float* __restrict__ Prel2) {
    int gid = blockIdx.x * 256 + threadIdx.x;
    int row = gid >> 6;
    int d = gid & 63;
    if (row < 1024) {
        const float* a = rel + (row >> 5) * DIMD;
        const float* c = rel + (row & 31) * DIMD;
        float acc = 0.0f;
#pragma unroll
        for (int k = 0; k < DIMD; ++k)
            acc = fmaf(a[k] * c[k], W1[(DIMD + k) * DIMD + d], acc);
        Prel2[row * DIMD + d] = acc;
    } else if (row < 1056) {
        const float* a = rel + (row - 1024) * DIMD;
        float acc = 0.0f;
#pragma unroll
        for (int k = 0; k < DIMD; ++k)
            acc = fmaf(a[k], W1[(DIMD + k) * DIMD + d], acc);
        Prel1[(row - 1024) * DIMD + d] = acc;
    }
}

// ---------------------------------------------------------------- main
// One block per b. Wave w = branch (0:uis->e_u, 1:ipt->e_i, 2:upt->e_p_u,
// 3:iot->e_p_i). Lane = (g = t-subgroup in [0,4), q = float4 chunk in [0,16)).
// tab: merged bf16 rows [entB(64) | PentB(64)], row stride 128 ushorts.
__global__ __launch_bounds__(256) void k_main(
    const int* __restrict__ items,
    const int* __restrict__ uh, const int* __restrict__ ur, const int* __restrict__ ut,
    const int* __restrict__ ih, const int* __restrict__ ir, const int* __restrict__ itp,
    const int* __restrict__ ph, const int* __restrict__ pr, const int* __restrict__ pt,
    const int* __restrict__ oh, const int* __restrict__ orr, const int* __restrict__ ot,
    const unsigned short* __restrict__ tab,
    const float* __restrict__ W2,
    const float* __restrict__ Prel1, const float* __restrict__ Prel2,
    float* __restrict__ out) {
    const int b = blockIdx.x;
    const int tid = threadIdx.x;
    const int w = tid >> 6;
    const int lane = tid & 63;
    const int g = lane >> 4;
    const int q = lane & 15;

    const int* hp;
    const int* rp;
    const int* tp;
    switch (w) {
        case 0: hp = uh; rp = ur; tp = ut; break;
        case 1: hp = ih; rp = ir; tp = itp; break;
        case 2: hp = ph; rp = pr; tp = pt; break;
        default: hp = oh; rp = orr; tp = ot; break;
    }

    // stage this block's indices in LDS (wave-private; same wave writes/reads)
    __shared__ int sidx[4][3][2][TT];
    {
        const int l = lane >> 5;
        const int t0 = lane & 31;
        const int off = l * BT + b * TT + t0;
        sidx[w][0][l][t0] = hp[off];
        sidx[w][1][l][t0] = rp[off];
        sidx[w][2][l][t0] = tp[off];
    }
    const int item_idx = (w == 1) ? items[b] : 0;

    const float4 w2v = ld4(W2 + 4 * q);

    // ---- Phase A: per-lane partial dots d0/d1 for all 8 t's (no reduces yet)
    float d0[8], d1[8];
    float4 accH = make_float4(0.f, 0.f, 0.f, 0.f);
#pragma unroll
    for (int p = 0; p < 8; ++p) {
        const int t = 4 * p + g;
        const int ih0 = sidx[w][0][0][t];
        const int ih1 = sidx[w][0][1][t];
        const int ir0 = sidx[w][1][0][t];
        const int ir1 = sidx[w][1][1][t];
        const unsigned short* row0p = tab + ((size_t)ih0 << 7);
        const float4 H  = ldb4(row0p + 4 * q);
        const float4 A0 = ldb4(row0p + 64 + 4 * q);
        const float4 A1 = ldb4(tab + ((size_t)ih1 << 7) + 64 + 4 * q);
        const float4 R0 = ld4(Prel1 + (ir0 << 6) + 4 * q);
        const float4 R2 = ld4(Prel2 + ((ir0 * 32 + ir1) << 6) + 4 * q);

        accH.x += H.x; accH.y += H.y; accH.z += H.z; accH.w += H.w;

        float v = sigf(A0.x + R0.x) * w2v.x;
        v = fmaf(sigf(A0.y + R0.y), w2v.y, v);
        v = fmaf(sigf(A0.z + R0.z), w2v.z, v);
        v = fmaf(sigf(A0.w + R0.w), w2v.w, v);
        d0[p] = v;

        float u = sigf(A0.x + A1.x + R2.x) * w2v.x;
        u = fmaf(sigf(A0.y + A1.y + R2.y), w2v.y, u);
        u = fmaf(sigf(A0.z + A1.z + R2.z), w2v.z, u);
        u = fmaf(sigf(A0.w + A1.w + R2.w), w2v.w, u);
        d1[p] = u;
    }

    // ---- Phase B: batched 16-lane DPP reduces; e = exp(sigmoid(dot)).
    float e0[8], e1[8];
    float s0 = 0.0f, s1 = 0.0f;
#pragma unroll
    for (int p = 0; p < 8; ++p) {
        e0[p] = __expf(sigf(reduce16(d0[p])));
        e1[p] = __expf(sigf(reduce16(d1[p])));
        s0 += e0[p];
        s1 += e1[p];
    }
    s0 += __shfl_xor(s0, 16, 64);
    s0 += __shfl_xor(s0, 32, 64);
    s1 += __shfl_xor(s1, 16, 64);
    s1 += __shfl_xor(s1, 32, 64);

    // ---- Phase C: unnormalized weighted t-emb sums (entB halves)
    float4 acc0 = make_float4(0.f, 0.f, 0.f, 0.f);
    float4 acc1 = acc0;
#pragma unroll
    for (int p = 0; p < 8; ++p) {
        const int t = 4 * p + g;
        const int it0 = sidx[w][2][0][t];
        const int it1 = sidx[w][2][1][t];
        const float4 T0 = ldb4(tab + ((size_t)it0 << 7) + 4 * q);
        const float4 T1 = ldb4(tab + ((size_t)it1 << 7) + 4 * q);
        acc0.x = fmaf(e0[p], T0.x, acc0.x); acc0.y = fmaf(e0[p], T0.y, acc0.y);
        acc0.z = fmaf(e0[p], T0.z, acc0.z); acc0.w = fmaf(e0[p], T0.w, acc0.w);
        acc1.x = fmaf(e1[p], T1.x, acc1.x); acc1.y = fmaf(e1[p], T1.y, acc1.y);
        acc1.z = fmaf(e1[p], T1.z, acc1.z); acc1.w = fmaf(e1[p], T1.w, acc1.w);
    }

    const float inv0 = 1.0f / s0;
    const float inv1 = 1.0f / s1;
    float4 v;
    v.x = fmaf(acc0.x, inv0, fmaf(acc1.x, inv1, 0.03125f * accH.x));
    v.y = fmaf(acc0.y, inv0, fmaf(acc1.y, inv1, 0.03125f * accH.y));
    v.z = fmaf(acc0.z, inv0, fmaf(acc1.z, inv1, 0.03125f * accH.z));
    v.w = fmaf(acc0.w, inv0, fmaf(acc1.w, inv1, 0.03125f * accH.w));

    // reduce across the 4 t-subgroups
    v.x += __shfl_xor(v.x, 16, 64); v.x += __shfl_xor(v.x, 32, 64);
    v.y += __shfl_xor(v.y, 16, 64); v.y += __shfl_xor(v.y, 32, 64);
    v.z += __shfl_xor(v.z, 16, 64); v.z += __shfl_xor(v.z, 32, 64);
    v.w += __shfl_xor(v.w, 16, 64); v.w += __shfl_xor(v.w, 32, 64);

    if (w == 1) {  // item branch additionally adds ent[items[b]] (entB half)
        const float4 iv = ldb4(tab + ((size_t)item_idx << 7) + 4 * q);
        v.x += iv.x; v.y += iv.y; v.z += iv.z; v.w += iv.w;
    }

    __shared__ float vec[4][DIMD];
    if (g == 0) {
        vec[w][4 * q + 0] = v.x;
        vec[w][4 * q + 1] = v.y;
        vec[w][4 * q + 2] = v.z;
        vec[w][4 * q + 3] = v.w;
    }
    __syncthreads();

    // score = sigmoid( sum_d e_u*e_p_i + e_p_u*e_i )
    if (tid < 64) {
        float z = fmaf(vec[0][tid], vec[3][tid], vec[2][tid] * vec[1][tid]);
#pragma unroll
        for (int m = 1; m < 64; m <<= 1) z += __shfl_xor(z, m, 64);
        if (tid == 0) out[b] = sigf(z);
    }
    if (b == 0 && tid == 0) out[BB] = 0.0f;  // kge_loss
}

extern "C" void kernel_launch(void* const* d_in, const int* in_sizes, int n_in,
                              void* d_out, int out_size, void* d_ws, size_t ws_size,
                              hipStream_t stream) {
    const int* items = (const int*)d_in[0];
    const int* uh = (const int*)d_in[1];
    const int* ur = (const int*)d_in[2];
    const int* ut = (const int*)d_in[3];
    const int* ih = (const int*)d_in[4];
    const int* ir = (const int*)d_in[5];
    const int* itp = (const int*)d_in[6];
    const int* ph = (const int*)d_in[7];
    const int* pr = (const int*)d_in[8];
    const int* pt = (const int*)d_in[9];
    const int* oh = (const int*)d_in[10];
    const int* orr = (const int*)d_in[11];
    const int* ot = (const int*)d_in[12];
    const float* ent = (const float*)d_in[13];
    const float* rel = (const float*)d_in[14];
    const float* W1 = (const float*)d_in[15];
    const float* W2 = (const float*)d_in[16];
    float* out = (float*)d_out;

    float* Prel1 = (float*)d_ws;                        // 32*64 f32
    float* Prel2 = Prel1 + NR * DIMD;                   // 1024*64 f32
    unsigned short* tab =
        (unsigned short*)(Prel2 + 1024 * DIMD);         // NE x 128 bf16 = 25.6MB

    hipLaunchKernelGGL(k_proj_ent, dim3((NE + 63) / 64), dim3(256), 0, stream,
                       ent, W1, tab);
    hipLaunchKernelGGL(k_proj_rel, dim3((1056 * 64 + 255) / 256), dim3(256), 0,
                       stream, rel, W1, Prel1, Prel2);
    hipLaunchKernelGGL(k_main, dim3(BB), dim3(256), 0, stream, items, uh, ur, ut,
                       ih, ir, itp, ph, pr, pt, oh, orr, ot, tab, W2, Prel1,
                       Prel2, out);
}